// Round 3
// baseline (1566.084 us; speedup 1.0000x reference)
//
#include <hip/hip_runtime.h>
#include <cstdint>
#include <cstddef>

#define T_DIM 4096
#define H_DIM 4096
#define I_DIM 11008

typedef int v4i  __attribute__((ext_vector_type(4)));
typedef int v16i __attribute__((ext_vector_type(16)));

// ---------------------------------------------------------------------------
// async global->LDS copy, 16B per lane (global_load_lds_dwordx4)
// ---------------------------------------------------------------------------
__device__ __forceinline__ void async_copy16(const void* g, void* l) {
  __builtin_amdgcn_global_load_lds(
      (const __attribute__((address_space(1))) void*)g,
      (__attribute__((address_space(3))) void*)l, 16, 0, 0);
}

// Stage a 128x128 int8 tile (row-major, leading dim ld) into 16 KB of LDS.
// LDS: row r at [r*128, r*128+128), 8 chunks of 16B. XOR swizzle on the
// GLOBAL source address (DMA dest is wave-uniform base + lane*16):
// physical chunk p holds logical chunk p ^ (r & 7).
// 8 waves: wave w stages rows [16w, 16w+16) via 2 copy ops (8 rows each).
__device__ __forceinline__ void stage_tile128(const int8_t* src, size_t ld,
                                              char* ldsbase, int wave, int lane) {
#pragma unroll
  for (int q = 0; q < 2; ++q) {
    int r = wave * 16 + q * 8 + (lane >> 3);   // tile row 0..127
    int p = lane & 7;                          // physical 16B chunk
    int c = p ^ (r & 7);                       // logical k chunk
    const int8_t* g = src + (size_t)r * ld + (size_t)c * 16;
    char* lp = ldsbase + (wave * 16 + q * 8) * 128;  // wave-uniform; HW adds lane*16
    async_copy16((const void*)g, (void*)lp);
  }
}

// 32x32x32 i8 A/B fragment from a swizzled 128B-row tile.
// lane holds row rowbase+(lane&31), 16B of K at logical chunk kc+(lane>>5).
// (k-permutation identical for A and B -> cancels in the dot product.)
__device__ __forceinline__ v4i frag128(const char* tile, int rowbase,
                                       int kc, int lane) {
  int r = rowbase + (lane & 31);
  int c = (kc + (lane >> 5)) ^ (r & 7);
  return *(const v4i*)(tile + r * 128 + c * 16);
}

// ---------------------------------------------------------------------------
// int32 -> int8 pack, 16 elements/thread (16B stores)
// ---------------------------------------------------------------------------
__global__ void pack_i8(const int4* __restrict__ src, v4i* __restrict__ dst, int n16) {
  int stride = gridDim.x * blockDim.x;
  for (int i = blockIdx.x * blockDim.x + threadIdx.x; i < n16; i += stride) {
    int4 a = src[4 * i + 0], b = src[4 * i + 1];
    int4 c = src[4 * i + 2], d = src[4 * i + 3];
    v4i o;
    o[0] = (a.x & 255) | ((a.y & 255) << 8) | ((a.z & 255) << 16) | (a.w << 24);
    o[1] = (b.x & 255) | ((b.y & 255) << 8) | ((b.z & 255) << 16) | (b.w << 24);
    o[2] = (c.x & 255) | ((c.y & 255) << 8) | ((c.z & 255) << 16) | (c.w << 24);
    o[3] = (d.x & 255) | ((d.y & 255) << 8) | ((d.z & 255) << 16) | (d.w << 24);
    dst[i] = o;
  }
}

__global__ void zero_u32(unsigned* __restrict__ p, int n) {
  int i = blockIdx.x * blockDim.x + threadIdx.x;
  if (i < n) p[i] = 0u;
}

// ---------------------------------------------------------------------------
// GEMM1 fused. Block: 512 threads = 8 waves, C-tile 128 rows x 128 cols of
// BOTH gate and up (shared A tile). Wave (wm=w>>2, wn=w&3): 64 rows x 32 cols,
// acc = accg[2] + accu[2] v16i = 64 regs -> 4 waves/SIMD, 16 waves/CU.
// BK=128, 2-barrier K-loop (staging strictly separated from ds_reads:
// R2 showed concurrent DMA-write/ds_read costs ~4 conflict cy per read).
// Epilogue: y = silu(g)*u fp32 store + per-row absmax atomicMax.
// ---------------------------------------------------------------------------
__global__ __launch_bounds__(512, 4)
void gemm1_silu(const int8_t* __restrict__ x8,
                const int8_t* __restrict__ wgu8,
                const float* __restrict__ x_scale,
                const float* __restrict__ s_wgu,
                float* __restrict__ y,
                unsigned* __restrict__ rowmax) {
  __shared__ __align__(16) char lds[49152];   // A 16K | Bg 16K | Bu 16K
  char* ldsA  = lds;
  char* ldsBg = lds + 16384;
  char* ldsBu = lds + 32768;

  const int tid = threadIdx.x;
  const int wave = tid >> 6, lane = tid & 63;
  const int wm = wave >> 2;        // 0..1: 64-row strip
  const int wn = wave & 3;         // 0..3: 32-col strip
  const int m0 = blockIdx.y * 128;
  const int n0 = blockIdx.x * 128;

  v16i accg[2], accu[2];
#pragma unroll
  for (int i = 0; i < 2; i++) {
#pragma unroll
    for (int e = 0; e < 16; e++) { accg[i][e] = 0; accu[i][e] = 0; }
  }

  const int8_t* Ab  = x8 + (size_t)m0 * H_DIM;
  const int8_t* Bgb = wgu8 + (size_t)n0 * H_DIM;
  const int8_t* Bub = wgu8 + ((size_t)I_DIM + (size_t)n0) * H_DIM;

  for (int k0 = 0; k0 < H_DIM; k0 += 128) {
    __syncthreads();                               // previous compute done
    stage_tile128(Ab + k0, H_DIM, ldsA, wave, lane);
    stage_tile128(Bgb + k0, H_DIM, ldsBg, wave, lane);
    stage_tile128(Bub + k0, H_DIM, ldsBu, wave, lane);
    __syncthreads();                               // staging drained
#pragma unroll
    for (int ks = 0; ks < 4; ++ks) {               // four K=32 steps
      v4i a0 = frag128(ldsA,  wm * 64,      ks * 2, lane);
      v4i a1 = frag128(ldsA,  wm * 64 + 32, ks * 2, lane);
      v4i bg = frag128(ldsBg, wn * 32,      ks * 2, lane);
      v4i bu = frag128(ldsBu, wn * 32,      ks * 2, lane);
      accg[0] = __builtin_amdgcn_mfma_i32_32x32x32_i8(a0, bg, accg[0], 0, 0, 0);
      accu[0] = __builtin_amdgcn_mfma_i32_32x32x32_i8(a0, bu, accu[0], 0, 0, 0);
      accg[1] = __builtin_amdgcn_mfma_i32_32x32x32_i8(a1, bg, accg[1], 0, 0, 0);
      accu[1] = __builtin_amdgcn_mfma_i32_32x32x32_i8(a1, bu, accu[1], 0, 0, 0);
    }
  }

  // Epilogue. 32x32 C/D layout: col = lane&31, row = (r&3)+8*(r>>2)+4*(lane>>5).
  const int lc = lane & 31;
  const int lh = lane >> 5;
  const int gc = n0 + wn * 32 + lc;
  const float swg = s_wgu[gc];
  const float swu = s_wgu[I_DIM + gc];
#pragma unroll
  for (int i = 0; i < 2; i++) {
#pragma unroll
    for (int r = 0; r < 16; r++) {
      const int gr = m0 + wm * 64 + i * 32 + (r & 3) + 8 * (r >> 2) + 4 * lh;
      const float sx = x_scale[gr];
      float g = (float)accg[i][r] * sx * swg;
      float u = (float)accu[i][r] * sx * swu;
      float yv = (g / (1.f + expf(-g))) * u;       // silu(g) * u
      y[(size_t)gr * I_DIM + gc] = yv;
      float vmax = fabsf(yv);
      // lanes sharing this row: the 32 lanes with the same lane>>5
#pragma unroll
      for (int off = 1; off < 32; off <<= 1)
        vmax = fmaxf(vmax, __shfl_xor(vmax, off, 64));
      if (lc == 0) atomicMax(&rowmax[gr], __float_as_uint(vmax));
    }
  }
}

// ---------------------------------------------------------------------------
// quantize y -> int8, 16 elems/thread. s2 = max(|y|,1e-8)/127, round-half-even
// ---------------------------------------------------------------------------
__global__ void quantize_y(const float* __restrict__ y,
                           const unsigned* __restrict__ rowmax,
                           v4i* __restrict__ yq) {
  size_t i = (size_t)blockIdx.x * blockDim.x + threadIdx.x;
  if (i >= (size_t)T_DIM * I_DIM / 16) return;
  size_t base = i * 16;
  int row = (int)(base / I_DIM);   // I_DIM % 16 == 0: packs never cross rows
  float inv = 127.f / fmaxf(__uint_as_float(rowmax[row]), 1e-8f);
  const float4* p = (const float4*)(y + base);
  v4i o;
#pragma unroll
  for (int q = 0; q < 4; q++) {
    float4 v = p[q];
    int b0 = (int)fminf(127.f, fmaxf(-128.f, rintf(v.x * inv)));
    int b1 = (int)fminf(127.f, fmaxf(-128.f, rintf(v.y * inv)));
    int b2 = (int)fminf(127.f, fmaxf(-128.f, rintf(v.z * inv)));
    int b3 = (int)fminf(127.f, fmaxf(-128.f, rintf(v.w * inv)));
    o[q] = (b0 & 255) | ((b1 & 255) << 8) | ((b2 & 255) << 16) | (b3 << 24);
  }
  yq[i] = o;
}

// ---------------------------------------------------------------------------
// GEMM2: out = (y_q @ w_down^T) * s2[row] * s_w_down[col]
// Same structure: 512 threads, wave = 64x32 tile, acc 32 regs, BK=128.
// ---------------------------------------------------------------------------
__global__ __launch_bounds__(512, 4)
void gemm2_scaled(const int8_t* __restrict__ yq8,
                  const int8_t* __restrict__ wd8,
                  const unsigned* __restrict__ rowmax,
                  const float* __restrict__ s_wd,
                  float* __restrict__ out) {
  __shared__ __align__(16) char lds[32768];   // A 16K | B 16K
  char* ldsA = lds;
  char* ldsB = lds + 16384;

  const int tid = threadIdx.x;
  const int wave = tid >> 6, lane = tid & 63;
  const int wm = wave >> 2;
  const int wn = wave & 3;
  const int m0 = blockIdx.y * 128;
  const int n0 = blockIdx.x * 128;

  v16i acc[2];
#pragma unroll
  for (int i = 0; i < 2; i++)
#pragma unroll
    for (int e = 0; e < 16; e++) acc[i][e] = 0;

  const int8_t* Ab = yq8 + (size_t)m0 * I_DIM;
  const int8_t* Bb = wd8 + (size_t)n0 * I_DIM;

  for (int k0 = 0; k0 < I_DIM; k0 += 128) {     // 86 iterations exactly
    __syncthreads();
    stage_tile128(Ab + k0, I_DIM, ldsA, wave, lane);
    stage_tile128(Bb + k0, I_DIM, ldsB, wave, lane);
    __syncthreads();
#pragma unroll
    for (int ks = 0; ks < 4; ++ks) {
      v4i a0 = frag128(ldsA, wm * 64,      ks * 2, lane);
      v4i a1 = frag128(ldsA, wm * 64 + 32, ks * 2, lane);
      v4i b  = frag128(ldsB, wn * 32,      ks * 2, lane);
      acc[0] = __builtin_amdgcn_mfma_i32_32x32x32_i8(a0, b, acc[0], 0, 0, 0);
      acc[1] = __builtin_amdgcn_mfma_i32_32x32x32_i8(a1, b, acc[1], 0, 0, 0);
    }
  }

  const int lc = lane & 31;
  const int lh = lane >> 5;
  const int gc = n0 + wn * 32 + lc;
  const float swd = s_wd[gc];
#pragma unroll
  for (int i = 0; i < 2; i++) {
#pragma unroll
    for (int r = 0; r < 16; r++) {
      const int gr = m0 + wm * 64 + i * 32 + (r & 3) + 8 * (r >> 2) + 4 * lh;
      const float s2 = fmaxf(__uint_as_float(rowmax[gr]), 1e-8f) / 127.f;
      out[(size_t)gr * H_DIM + gc] = (float)acc[i][r] * s2 * swd;
    }
  }
}

// ---------------------------------------------------------------------------
// launch
// ---------------------------------------------------------------------------
extern "C" void kernel_launch(void* const* d_in, const int* in_sizes, int n_in,
                              void* d_out, int out_size, void* d_ws, size_t ws_size,
                              hipStream_t stream) {
  const int*   x_q     = (const int*)d_in[0];
  const float* x_scale = (const float*)d_in[1];
  const int*   w_gu    = (const int*)d_in[2];
  const float* s_wgu   = (const float*)d_in[3];
  const int*   w_d     = (const int*)d_in[4];
  const float* s_wd    = (const float*)d_in[5];
  float* out = (float*)d_out;

  char* ws = (char*)d_ws;
  const size_t SZ_X8   = (size_t)T_DIM * H_DIM;
  const size_t SZ_WGU8 = (size_t)2 * I_DIM * H_DIM;
  const size_t SZ_WD8  = (size_t)H_DIM * I_DIM;
  const size_t SZ_Y    = (size_t)T_DIM * I_DIM * 4;
  const size_t SZ_YQ   = (size_t)T_DIM * I_DIM;

  int8_t*   x8     = (int8_t*)ws;
  int8_t*   wgu8   = (int8_t*)(ws + SZ_X8);
  int8_t*   wd8    = (int8_t*)(ws + SZ_X8 + SZ_WGU8);
  float*    y      = (float*)(ws + SZ_X8 + SZ_WGU8 + SZ_WD8);
  int8_t*   yq8    = (int8_t*)(ws + SZ_X8 + SZ_WGU8 + SZ_WD8 + SZ_Y);
  unsigned* rowmax = (unsigned*)(ws + SZ_X8 + SZ_WGU8 + SZ_WD8 + SZ_Y + SZ_YQ);

  pack_i8<<<dim3(4096), dim3(256), 0, stream>>>((const int4*)x_q,  (v4i*)x8,   (int)(SZ_X8 / 16));
  pack_i8<<<dim3(4096), dim3(256), 0, stream>>>((const int4*)w_gu, (v4i*)wgu8, (int)(SZ_WGU8 / 16));
  pack_i8<<<dim3(4096), dim3(256), 0, stream>>>((const int4*)w_d,  (v4i*)wd8,  (int)(SZ_WD8 / 16));
  zero_u32<<<dim3(16), dim3(256), 0, stream>>>(rowmax, T_DIM);

  gemm1_silu<<<dim3(I_DIM / 128, T_DIM / 128), dim3(512), 0, stream>>>(
      x8, wgu8, x_scale, s_wgu, y, rowmax);

  quantize_y<<<dim3((unsigned)(((size_t)T_DIM * I_DIM / 16 + 255) / 256)), dim3(256), 0, stream>>>(
      y, rowmax, (v4i*)yq8);

  gemm2_scaled<<<dim3(H_DIM / 128, T_DIM / 128), dim3(512), 0, stream>>>(
      yq8, wd8, rowmax, s_wd, out);
}